// Round 2
// baseline (976.175 us; speedup 1.0000x reference)
//
#include <hip/hip_runtime.h>

#define B_N 65536
#define M_N 1000000
#define E_N 1310720
#define IN_D 64
#define OUT_D 32
#define XS 68  // sx row stride in shorts (136 B: 8B-aligned rows, stride-34-dword banks)

__device__ __forceinline__ unsigned short f2bf(float f) {
  unsigned u = __float_as_uint(f);
  u += 0x7fffu + ((u >> 16) & 1u);
  return (unsigned short)(u >> 16);
}
__device__ __forceinline__ unsigned pk2(float a, float b) {
  return (unsigned)f2bf(a) | ((unsigned)f2bf(b) << 16);
}

// Kernel 1: stage 256 emb rows/block into LDS (coalesced, bf16), then
// h_bal/h_unbal = x@W (bf16 out), adst = h.a[OUT:], asrc = h.a[:OUT] (n<B).
__global__ __launch_bounds__(256) void k_hproj(
    const float* __restrict__ emb,
    const float* __restrict__ Wb, const float* __restrict__ ab,
    const float* __restrict__ Wu, const float* __restrict__ au,
    const int* __restrict__ uids,
    unsigned short* __restrict__ hb, unsigned short* __restrict__ hu,
    float* __restrict__ adb, float* __restrict__ adu,
    float* __restrict__ asb, float* __restrict__ asu)
{
  __shared__ float sWb[IN_D][OUT_D];
  __shared__ float sWu[IN_D][OUT_D];
  __shared__ float sab[2 * OUT_D];
  __shared__ float sau[2 * OUT_D];
  __shared__ int suid[256];
  __shared__ unsigned short sx[256 * XS];

  int t = threadIdx.x;
  for (int i = t; i < IN_D * OUT_D; i += 256) {
    sWb[i >> 5][i & 31] = Wb[i];
    sWu[i >> 5][i & 31] = Wu[i];
  }
  if (t < 2 * OUT_D) {
    sab[t] = ab[t];
    sau[t] = au[t];
  }
  int nbase = blockIdx.x * 256;
  int n = nbase + t;
  suid[t] = (n < M_N) ? uids[n] : 0;
  __syncthreads();

  // Stage: iter i loads rows [16i, 16i+16); thread t handles chunk (t&15) of
  // row 16i + (t>>4). Per wave: 4 rows x 256 B contiguous = 1 KB/instr.
  int chunk = t & 15;
  int rb = t >> 4;
  #pragma unroll 4
  for (int i = 0; i < 16; ++i) {
    int row = i * 16 + rb;
    int uid = suid[row];
    float4 v = ((const float4*)emb)[(size_t)uid * 16 + chunk];
    uint2 p;
    p.x = pk2(v.x, v.y);
    p.y = pk2(v.z, v.w);
    *(uint2*)(&sx[row * XS + chunk * 4]) = p;
  }
  __syncthreads();

  if (n >= M_N) return;
  const unsigned short* xrow = &sx[t * XS];

  float accb[OUT_D], accu[OUT_D];
  #pragma unroll
  for (int j = 0; j < OUT_D; ++j) { accb[j] = 0.f; accu[j] = 0.f; }

  #pragma unroll
  for (int kc = 0; kc < 16; ++kc) {
    uint2 xx = *(const uint2*)(xrow + kc * 4);
    float xk4[4];
    xk4[0] = __uint_as_float(xx.x << 16);
    xk4[1] = __uint_as_float(xx.x & 0xffff0000u);
    xk4[2] = __uint_as_float(xx.y << 16);
    xk4[3] = __uint_as_float(xx.y & 0xffff0000u);
    #pragma unroll
    for (int dk = 0; dk < 4; ++dk) {
      int k = kc * 4 + dk;
      float xk = xk4[dk];
      const float4* wb4 = (const float4*)(&sWb[k][0]);
      const float4* wu4 = (const float4*)(&sWu[k][0]);
      #pragma unroll
      for (int j4 = 0; j4 < 8; ++j4) {
        float4 wb = wb4[j4];
        float4 wu = wu4[j4];
        accb[4 * j4 + 0] = fmaf(xk, wb.x, accb[4 * j4 + 0]);
        accb[4 * j4 + 1] = fmaf(xk, wb.y, accb[4 * j4 + 1]);
        accb[4 * j4 + 2] = fmaf(xk, wb.z, accb[4 * j4 + 2]);
        accb[4 * j4 + 3] = fmaf(xk, wb.w, accb[4 * j4 + 3]);
        accu[4 * j4 + 0] = fmaf(xk, wu.x, accu[4 * j4 + 0]);
        accu[4 * j4 + 1] = fmaf(xk, wu.y, accu[4 * j4 + 1]);
        accu[4 * j4 + 2] = fmaf(xk, wu.z, accu[4 * j4 + 2]);
        accu[4 * j4 + 3] = fmaf(xk, wu.w, accu[4 * j4 + 3]);
      }
    }
  }

  float adotb = 0.f, adotu = 0.f, asrcb = 0.f, asrcu = 0.f;
  #pragma unroll
  for (int j = 0; j < OUT_D; ++j) {
    asrcb = fmaf(accb[j], sab[j], asrcb);
    adotb = fmaf(accb[j], sab[OUT_D + j], adotb);
    asrcu = fmaf(accu[j], sau[j], asrcu);
    adotu = fmaf(accu[j], sau[OUT_D + j], adotu);
  }
  adb[n] = adotb;
  adu[n] = adotu;
  if (n < B_N) { asb[n] = asrcb; asu[n] = asrcu; }

  uint4* hb4 = (uint4*)(hb + (size_t)n * OUT_D);
  uint4* hu4 = (uint4*)(hu + (size_t)n * OUT_D);
  #pragma unroll
  for (int q = 0; q < 4; ++q) {
    uint4 v, w;
    v.x = pk2(accb[8 * q + 0], accb[8 * q + 1]);
    v.y = pk2(accb[8 * q + 2], accb[8 * q + 3]);
    v.z = pk2(accb[8 * q + 4], accb[8 * q + 5]);
    v.w = pk2(accb[8 * q + 6], accb[8 * q + 7]);
    w.x = pk2(accu[8 * q + 0], accu[8 * q + 1]);
    w.y = pk2(accu[8 * q + 2], accu[8 * q + 3]);
    w.z = pk2(accu[8 * q + 4], accu[8 * q + 5]);
    w.w = pk2(accu[8 * q + 6], accu[8 * q + 7]);
    hb4[q] = v;
    hu4[q] = w;
  }
}

// Kernel 2: edge aggregation. 16 lanes/edge (4 edges/wave); lane handles 2 cols.
__global__ __launch_bounds__(256) void k_edge(
    const int* __restrict__ selfc,
    const int* __restrict__ erows, const int* __restrict__ ecols,
    const unsigned* __restrict__ h2,
    const float* __restrict__ adst, const float* __restrict__ asrc,
    float* __restrict__ num, float* __restrict__ den)
{
  int g = blockIdx.x * 16 + (threadIdx.x >> 4);
  int lane = threadIdx.x & 15;
  if (g >= B_N + E_N) return;
  int r, c;
  if (g < B_N) { r = g; c = selfc[g]; }
  else { r = erows[g - B_N]; c = ecols[g - B_N]; }
  float s = asrc[r] + adst[c];
  float sc = s > 0.f ? s : 0.2f * s;
  float ev = __expf(-sc);
  unsigned hv = h2[(size_t)c * 16 + lane];
  float h0 = __uint_as_float(hv << 16);
  float h1 = __uint_as_float(hv & 0xffff0000u);
  float* np = num + (((size_t)r) << 5) + (lane << 1);
  atomicAdd(np, ev * h0);
  atomicAdd(np + 1, ev * h1);
  if (lane == 0) atomicAdd(den + r, ev);
}

// Kernel 3: out = elu(num/den) for both branches.
__global__ __launch_bounds__(256) void k_fin(
    const float* __restrict__ numb, const float* __restrict__ denb,
    const float* __restrict__ numu, const float* __restrict__ denu,
    float* __restrict__ out)
{
  int i = blockIdx.x * 256 + threadIdx.x;
  if (i >= B_N * OUT_D) return;
  int r = i >> 5;
  float xb = numb[i] / denb[r];
  out[i] = (xb > 0.f) ? xb : (__expf(xb) - 1.f);
  float xu = numu[i] / denu[r];
  out[B_N * OUT_D + i] = (xu > 0.f) ? xu : (__expf(xu) - 1.f);
}

extern "C" void kernel_launch(void* const* d_in, const int* in_sizes, int n_in,
                              void* d_out, int out_size, void* d_ws, size_t ws_size,
                              hipStream_t stream) {
  const float* emb = (const float*)d_in[0];
  const float* Wb  = (const float*)d_in[1];
  const float* ab  = (const float*)d_in[2];
  const float* Wu  = (const float*)d_in[3];
  const float* au  = (const float*)d_in[4];
  const int* uids  = (const int*)d_in[5];
  const int* selfc = (const int*)d_in[6];
  const int* prow  = (const int*)d_in[7];
  const int* pcol  = (const int*)d_in[8];
  const int* nrow  = (const int*)d_in[9];
  const int* ncol  = (const int*)d_in[10];
  float* out = (float*)d_out;

  char* ws = (char*)d_ws;
  size_t off = 0;
  auto alloc = [&](size_t bytes) -> void* {
    void* p = ws + off;
    off += (bytes + 255) & ~(size_t)255;
    return p;
  };
  unsigned short* hb = (unsigned short*)alloc((size_t)M_N * OUT_D * 2);
  unsigned short* hu = (unsigned short*)alloc((size_t)M_N * OUT_D * 2);
  float* adb = (float*)alloc((size_t)M_N * 4);
  float* adu = (float*)alloc((size_t)M_N * 4);
  float* asb = (float*)alloc((size_t)B_N * 4);
  float* asu = (float*)alloc((size_t)B_N * 4);
  char* zbase = ws + off;
  float* numb = (float*)alloc((size_t)B_N * OUT_D * 4);
  float* numu = (float*)alloc((size_t)B_N * OUT_D * 4);
  float* denb = (float*)alloc((size_t)B_N * 4);
  float* denu = (float*)alloc((size_t)B_N * 4);
  size_t zbytes = (size_t)((ws + off) - zbase);

  hipMemsetAsync(zbase, 0, zbytes, stream);

  k_hproj<<<(M_N + 255) / 256, 256, 0, stream>>>(emb, Wb, ab, Wu, au, uids,
                                                 hb, hu, adb, adu, asb, asu);

  int egroups = B_N + E_N;
  int eblocks = (egroups + 15) / 16;
  k_edge<<<eblocks, 256, 0, stream>>>(selfc, prow, pcol, (const unsigned*)hb,
                                      adb, asb, numb, denb);
  k_edge<<<eblocks, 256, 0, stream>>>(selfc, nrow, ncol, (const unsigned*)hu,
                                      adu, asu, numu, denu);

  k_fin<<<(B_N * OUT_D + 255) / 256, 256, 0, stream>>>(numb, denb, numu, denu, out);
}

// Round 3
// 782.932 us; speedup vs baseline: 1.2468x; 1.2468x over previous
//
#include <hip/hip_runtime.h>

#define B_N 65536
#define M_N 1000000
#define E_N 1310720
#define IN_D 64
#define OUT_D 32
#define XS 68  // sx row stride in shorts (136 B: 8B-aligned rows, stride-34-dword banks)

__device__ __forceinline__ unsigned short f2bf(float f) {
  unsigned u = __float_as_uint(f);
  u += 0x7fffu + ((u >> 16) & 1u);
  return (unsigned short)(u >> 16);
}
__device__ __forceinline__ unsigned pk2(float a, float b) {
  return (unsigned)f2bf(a) | ((unsigned)f2bf(b) << 16);
}
__device__ __forceinline__ float bf2f(unsigned short s) {
  return __uint_as_float(((unsigned)s) << 16);
}

// Kernel 1: stage 256 emb rows/block into LDS (coalesced, bf16), then
// h_bal/h_unbal = x@W (bf16 out), adst = h.a[OUT:], asrc = h.a[:OUT] (n<B).
__global__ __launch_bounds__(256) void k_hproj(
    const float* __restrict__ emb,
    const float* __restrict__ Wb, const float* __restrict__ ab,
    const float* __restrict__ Wu, const float* __restrict__ au,
    const int* __restrict__ uids,
    unsigned short* __restrict__ hb, unsigned short* __restrict__ hu,
    float* __restrict__ adb, float* __restrict__ adu,
    float* __restrict__ asb, float* __restrict__ asu)
{
  __shared__ float sWb[IN_D][OUT_D];
  __shared__ float sWu[IN_D][OUT_D];
  __shared__ float sab[2 * OUT_D];
  __shared__ float sau[2 * OUT_D];
  __shared__ int suid[256];
  __shared__ unsigned short sx[256 * XS];

  int t = threadIdx.x;
  for (int i = t; i < IN_D * OUT_D; i += 256) {
    sWb[i >> 5][i & 31] = Wb[i];
    sWu[i >> 5][i & 31] = Wu[i];
  }
  if (t < 2 * OUT_D) {
    sab[t] = ab[t];
    sau[t] = au[t];
  }
  int nbase = blockIdx.x * 256;
  int n = nbase + t;
  suid[t] = (n < M_N) ? uids[n] : 0;
  __syncthreads();

  // Stage: iter i loads rows [16i, 16i+16); thread t handles chunk (t&15) of
  // row 16i + (t>>4). Per wave: 4 rows x 256 B contiguous = 1 KB/instr.
  int chunk = t & 15;
  int rb = t >> 4;
  #pragma unroll 4
  for (int i = 0; i < 16; ++i) {
    int row = i * 16 + rb;
    int uid = suid[row];
    float4 v = ((const float4*)emb)[(size_t)uid * 16 + chunk];
    uint2 p;
    p.x = pk2(v.x, v.y);
    p.y = pk2(v.z, v.w);
    *(uint2*)(&sx[row * XS + chunk * 4]) = p;
  }
  __syncthreads();

  if (n >= M_N) return;
  const unsigned short* xrow = &sx[t * XS];

  float accb[OUT_D], accu[OUT_D];
  #pragma unroll
  for (int j = 0; j < OUT_D; ++j) { accb[j] = 0.f; accu[j] = 0.f; }

  #pragma unroll
  for (int kc = 0; kc < 16; ++kc) {
    uint2 xx = *(const uint2*)(xrow + kc * 4);
    float xk4[4];
    xk4[0] = __uint_as_float(xx.x << 16);
    xk4[1] = __uint_as_float(xx.x & 0xffff0000u);
    xk4[2] = __uint_as_float(xx.y << 16);
    xk4[3] = __uint_as_float(xx.y & 0xffff0000u);
    #pragma unroll
    for (int dk = 0; dk < 4; ++dk) {
      int k = kc * 4 + dk;
      float xk = xk4[dk];
      const float4* wb4 = (const float4*)(&sWb[k][0]);
      const float4* wu4 = (const float4*)(&sWu[k][0]);
      #pragma unroll
      for (int j4 = 0; j4 < 8; ++j4) {
        float4 wb = wb4[j4];
        float4 wu = wu4[j4];
        accb[4 * j4 + 0] = fmaf(xk, wb.x, accb[4 * j4 + 0]);
        accb[4 * j4 + 1] = fmaf(xk, wb.y, accb[4 * j4 + 1]);
        accb[4 * j4 + 2] = fmaf(xk, wb.z, accb[4 * j4 + 2]);
        accb[4 * j4 + 3] = fmaf(xk, wb.w, accb[4 * j4 + 3]);
        accu[4 * j4 + 0] = fmaf(xk, wu.x, accu[4 * j4 + 0]);
        accu[4 * j4 + 1] = fmaf(xk, wu.y, accu[4 * j4 + 1]);
        accu[4 * j4 + 2] = fmaf(xk, wu.z, accu[4 * j4 + 2]);
        accu[4 * j4 + 3] = fmaf(xk, wu.w, accu[4 * j4 + 3]);
      }
    }
  }

  float adotb = 0.f, adotu = 0.f, asrcb = 0.f, asrcu = 0.f;
  #pragma unroll
  for (int j = 0; j < OUT_D; ++j) {
    asrcb = fmaf(accb[j], sab[j], asrcb);
    adotb = fmaf(accb[j], sab[OUT_D + j], adotb);
    asrcu = fmaf(accu[j], sau[j], asrcu);
    adotu = fmaf(accu[j], sau[OUT_D + j], adotu);
  }
  adb[n] = adotb;
  adu[n] = adotu;
  if (n < B_N) { asb[n] = asrcb; asu[n] = asrcu; }

  uint4* hb4 = (uint4*)(hb + (size_t)n * OUT_D);
  uint4* hu4 = (uint4*)(hu + (size_t)n * OUT_D);
  #pragma unroll
  for (int q = 0; q < 4; ++q) {
    uint4 v, w;
    v.x = pk2(accb[8 * q + 0], accb[8 * q + 1]);
    v.y = pk2(accb[8 * q + 2], accb[8 * q + 3]);
    v.z = pk2(accb[8 * q + 4], accb[8 * q + 5]);
    v.w = pk2(accb[8 * q + 6], accb[8 * q + 7]);
    w.x = pk2(accu[8 * q + 0], accu[8 * q + 1]);
    w.y = pk2(accu[8 * q + 2], accu[8 * q + 3]);
    w.z = pk2(accu[8 * q + 4], accu[8 * q + 5]);
    w.w = pk2(accu[8 * q + 6], accu[8 * q + 7]);
    hb4[q] = v;
    hu4[q] = w;
  }
}

// Kernel 2: fused edge aggregation, both branches. 32 lanes/edge, 1 atomic/lane
// into the XCD-local accumulator copy (workgroup-scope atomics stay in local L2).
__global__ __launch_bounds__(256) void k_edge(
    const int* __restrict__ selfc,
    const int* __restrict__ prow, const int* __restrict__ pcol,
    const int* __restrict__ nrow, const int* __restrict__ ncol,
    const unsigned short* __restrict__ hb, const unsigned short* __restrict__ hu,
    const float* __restrict__ adb, const float* __restrict__ asb,
    const float* __restrict__ adu, const float* __restrict__ asu,
    float* __restrict__ numB, float* __restrict__ denB,
    float* __restrict__ numU, float* __restrict__ denU,
    int nc)
{
  const int PER = B_N + E_N;
  int g = blockIdx.x * 8 + (threadIdx.x >> 5);
  int lane = threadIdx.x & 31;
  if (g >= 2 * PER) return;
  int branch = (g >= PER) ? 1 : 0;
  int gg = g - branch * PER;

  int r, c;
  if (gg < B_N) {
    r = gg; c = selfc[gg];
  } else {
    r = (branch ? nrow : prow)[gg - B_N];
    c = (branch ? ncol : pcol)[gg - B_N];
  }

  const float* asrc = branch ? asu : asb;
  const float* adst = branch ? adu : adb;
  const unsigned short* h = branch ? hu : hb;

  float s = asrc[r] + adst[c];
  float sc = s > 0.f ? s : 0.2f * s;
  float ev = __expf(-sc);
  float hv = bf2f(h[(size_t)c * OUT_D + lane]);

  unsigned xcc;
  asm volatile("s_getreg_b32 %0, hwreg(HW_REG_XCC_ID)" : "=s"(xcc));
  unsigned cp = xcc & (unsigned)(nc - 1);

  float* np = (branch ? numU : numB) + (size_t)cp * (B_N * OUT_D) + (((size_t)r) << 5) + lane;
  __hip_atomic_fetch_add(np, ev * hv, __ATOMIC_RELAXED, __HIP_MEMORY_SCOPE_WORKGROUP);
  if (lane == 0) {
    float* dp = (branch ? denU : denB) + (size_t)cp * B_N + r;
    __hip_atomic_fetch_add(dp, ev, __ATOMIC_RELAXED, __HIP_MEMORY_SCOPE_WORKGROUP);
  }
}

// Kernel 3: reduce the NC copies, divide, elu, write out (both branches).
__global__ __launch_bounds__(256) void k_red(
    const float* __restrict__ numB, const float* __restrict__ denB,
    const float* __restrict__ numU, const float* __restrict__ denU,
    float* __restrict__ out, int nc)
{
  int i = blockIdx.x * 256 + threadIdx.x;
  if (i >= B_N * OUT_D) return;
  int r = i >> 5;
  float nb = 0.f, db = 0.f, nu = 0.f, du = 0.f;
  for (int k = 0; k < nc; ++k) {
    nb += numB[(size_t)k * (B_N * OUT_D) + i];
    db += denB[(size_t)k * B_N + r];
    nu += numU[(size_t)k * (B_N * OUT_D) + i];
    du += denU[(size_t)k * B_N + r];
  }
  float xb = nb / db;
  out[i] = (xb > 0.f) ? xb : (__expf(xb) - 1.f);
  float xu = nu / du;
  out[B_N * OUT_D + i] = (xu > 0.f) ? xu : (__expf(xu) - 1.f);
}

extern "C" void kernel_launch(void* const* d_in, const int* in_sizes, int n_in,
                              void* d_out, int out_size, void* d_ws, size_t ws_size,
                              hipStream_t stream) {
  const float* emb = (const float*)d_in[0];
  const float* Wb  = (const float*)d_in[1];
  const float* ab  = (const float*)d_in[2];
  const float* Wu  = (const float*)d_in[3];
  const float* au  = (const float*)d_in[4];
  const int* uids  = (const int*)d_in[5];
  const int* selfc = (const int*)d_in[6];
  const int* prow  = (const int*)d_in[7];
  const int* pcol  = (const int*)d_in[8];
  const int* nrow  = (const int*)d_in[9];
  const int* ncol  = (const int*)d_in[10];
  float* out = (float*)d_out;

  char* ws = (char*)d_ws;
  size_t off = 0;
  auto alloc = [&](size_t bytes) -> void* {
    void* p = ws + off;
    off += (bytes + 255) & ~(size_t)255;
    return p;
  };
  unsigned short* hb = (unsigned short*)alloc((size_t)M_N * OUT_D * 2);
  unsigned short* hu = (unsigned short*)alloc((size_t)M_N * OUT_D * 2);
  float* adb = (float*)alloc((size_t)M_N * 4);
  float* adu = (float*)alloc((size_t)M_N * 4);
  float* asb = (float*)alloc((size_t)B_N * 4);
  float* asu = (float*)alloc((size_t)B_N * 4);

  // Per-XCD accumulator copies: pick largest power-of-2 NC (<=8) that fits.
  size_t per_copy = ((size_t)B_N * OUT_D + B_N) * 4;  // num + den, one branch
  int nc = 8;
  while (nc > 1 && off + (size_t)2 * nc * per_copy + 4096 > ws_size) nc >>= 1;

  char* zbase = ws + off;
  float* numB = (float*)alloc((size_t)nc * B_N * OUT_D * 4);
  float* denB = (float*)alloc((size_t)nc * B_N * 4);
  float* numU = (float*)alloc((size_t)nc * B_N * OUT_D * 4);
  float* denU = (float*)alloc((size_t)nc * B_N * 4);
  size_t zbytes = (size_t)((ws + off) - zbase);

  hipMemsetAsync(zbase, 0, zbytes, stream);

  k_hproj<<<(M_N + 255) / 256, 256, 0, stream>>>(emb, Wb, ab, Wu, au, uids,
                                                 hb, hu, adb, adu, asb, asu);

  int egroups = 2 * (B_N + E_N);
  int eblocks = (egroups + 7) / 8;
  k_edge<<<eblocks, 256, 0, stream>>>(selfc, prow, pcol, nrow, ncol,
                                      hb, hu, adb, asb, adu, asu,
                                      numB, denB, numU, denU, nc);

  k_red<<<(B_N * OUT_D + 255) / 256, 256, 0, stream>>>(numB, denB, numU, denU,
                                                       out, nc);
}

// Round 4
// 778.237 us; speedup vs baseline: 1.2543x; 1.0060x over previous
//
#include <hip/hip_runtime.h>

#define B_N 65536
#define M_N 1000000
#define E_N 1310720
#define IN_D 64
#define OUT_D 32
#define XS 68  // sx row stride in shorts (136 B: 8B-aligned rows, stride-34-dword banks)

__device__ __forceinline__ unsigned short f2bf(float f) {
  unsigned u = __float_as_uint(f);
  u += 0x7fffu + ((u >> 16) & 1u);
  return (unsigned short)(u >> 16);
}
__device__ __forceinline__ unsigned pk2(float a, float b) {
  return (unsigned)f2bf(a) | ((unsigned)f2bf(b) << 16);
}
__device__ __forceinline__ float bf2f(unsigned short s) {
  return __uint_as_float(((unsigned)s) << 16);
}

// Kernel 1: stage 256 emb rows/block into LDS (coalesced, bf16), then
// h_bal/h_unbal = x@W (bf16 out), adst = h.a[OUT:], asrc = h.a[:OUT] (n<B).
__global__ __launch_bounds__(256) void k_hproj(
    const float* __restrict__ emb,
    const float* __restrict__ Wb, const float* __restrict__ ab,
    const float* __restrict__ Wu, const float* __restrict__ au,
    const int* __restrict__ uids,
    unsigned short* __restrict__ hb, unsigned short* __restrict__ hu,
    float* __restrict__ adb, float* __restrict__ adu,
    float* __restrict__ asb, float* __restrict__ asu)
{
  __shared__ float sWb[IN_D][OUT_D];
  __shared__ float sWu[IN_D][OUT_D];
  __shared__ float sab[2 * OUT_D];
  __shared__ float sau[2 * OUT_D];
  __shared__ int suid[256];
  __shared__ unsigned short sx[256 * XS];

  int t = threadIdx.x;
  for (int i = t; i < IN_D * OUT_D; i += 256) {
    sWb[i >> 5][i & 31] = Wb[i];
    sWu[i >> 5][i & 31] = Wu[i];
  }
  if (t < 2 * OUT_D) {
    sab[t] = ab[t];
    sau[t] = au[t];
  }
  int nbase = blockIdx.x * 256;
  int n = nbase + t;
  suid[t] = (n < M_N) ? uids[n] : 0;
  __syncthreads();

  int chunk = t & 15;
  int rb = t >> 4;
  #pragma unroll 4
  for (int i = 0; i < 16; ++i) {
    int row = i * 16 + rb;
    int uid = suid[row];
    float4 v = ((const float4*)emb)[(size_t)uid * 16 + chunk];
    uint2 p;
    p.x = pk2(v.x, v.y);
    p.y = pk2(v.z, v.w);
    *(uint2*)(&sx[row * XS + chunk * 4]) = p;
  }
  __syncthreads();

  if (n >= M_N) return;
  const unsigned short* xrow = &sx[t * XS];

  float accb[OUT_D], accu[OUT_D];
  #pragma unroll
  for (int j = 0; j < OUT_D; ++j) { accb[j] = 0.f; accu[j] = 0.f; }

  #pragma unroll
  for (int kc = 0; kc < 16; ++kc) {
    uint2 xx = *(const uint2*)(xrow + kc * 4);
    float xk4[4];
    xk4[0] = __uint_as_float(xx.x << 16);
    xk4[1] = __uint_as_float(xx.x & 0xffff0000u);
    xk4[2] = __uint_as_float(xx.y << 16);
    xk4[3] = __uint_as_float(xx.y & 0xffff0000u);
    #pragma unroll
    for (int dk = 0; dk < 4; ++dk) {
      int k = kc * 4 + dk;
      float xk = xk4[dk];
      const float4* wb4 = (const float4*)(&sWb[k][0]);
      const float4* wu4 = (const float4*)(&sWu[k][0]);
      #pragma unroll
      for (int j4 = 0; j4 < 8; ++j4) {
        float4 wb = wb4[j4];
        float4 wu = wu4[j4];
        accb[4 * j4 + 0] = fmaf(xk, wb.x, accb[4 * j4 + 0]);
        accb[4 * j4 + 1] = fmaf(xk, wb.y, accb[4 * j4 + 1]);
        accb[4 * j4 + 2] = fmaf(xk, wb.z, accb[4 * j4 + 2]);
        accb[4 * j4 + 3] = fmaf(xk, wb.w, accb[4 * j4 + 3]);
        accu[4 * j4 + 0] = fmaf(xk, wu.x, accu[4 * j4 + 0]);
        accu[4 * j4 + 1] = fmaf(xk, wu.y, accu[4 * j4 + 1]);
        accu[4 * j4 + 2] = fmaf(xk, wu.z, accu[4 * j4 + 2]);
        accu[4 * j4 + 3] = fmaf(xk, wu.w, accu[4 * j4 + 3]);
      }
    }
  }

  float adotb = 0.f, adotu = 0.f, asrcb = 0.f, asrcu = 0.f;
  #pragma unroll
  for (int j = 0; j < OUT_D; ++j) {
    asrcb = fmaf(accb[j], sab[j], asrcb);
    adotb = fmaf(accb[j], sab[OUT_D + j], adotb);
    asrcu = fmaf(accu[j], sau[j], asrcu);
    adotu = fmaf(accu[j], sau[OUT_D + j], adotu);
  }
  adb[n] = adotb;
  adu[n] = adotu;
  if (n < B_N) { asb[n] = asrcb; asu[n] = asrcu; }

  uint4* hb4 = (uint4*)(hb + (size_t)n * OUT_D);
  uint4* hu4 = (uint4*)(hu + (size_t)n * OUT_D);
  #pragma unroll
  for (int q = 0; q < 4; ++q) {
    uint4 v, w;
    v.x = pk2(accb[8 * q + 0], accb[8 * q + 1]);
    v.y = pk2(accb[8 * q + 2], accb[8 * q + 3]);
    v.z = pk2(accb[8 * q + 4], accb[8 * q + 5]);
    v.w = pk2(accb[8 * q + 6], accb[8 * q + 7]);
    w.x = pk2(accu[8 * q + 0], accu[8 * q + 1]);
    w.y = pk2(accu[8 * q + 2], accu[8 * q + 3]);
    w.z = pk2(accu[8 * q + 4], accu[8 * q + 5]);
    w.w = pk2(accu[8 * q + 6], accu[8 * q + 7]);
    hb4[q] = v;
    hu4[q] = w;
  }
}

// Counting sort of edges by (branch, row) -> CSR.
__global__ __launch_bounds__(256) void k_hist(
    const int* __restrict__ prow, const int* __restrict__ nrow,
    int* __restrict__ hist)
{
  int i = blockIdx.x * 256 + threadIdx.x;
  if (i < E_N) atomicAdd(&hist[prow[i]], 1);
  else if (i < 2 * E_N) atomicAdd(&hist[B_N + nrow[i - E_N]], 1);
}

// Single-block exclusive scan of hist[2*B_N] -> start (and cursor copy).
__global__ __launch_bounds__(1024) void k_scan(
    const int* __restrict__ hist,
    int* __restrict__ start, int* __restrict__ cursor)
{
  __shared__ int s1[1024];
  int t = threadIdx.x;
  const int PER = (2 * B_N) / 1024;  // 128
  int base = t * PER;
  int sum = 0;
  for (int i = 0; i < PER; ++i) sum += hist[base + i];
  s1[t] = sum;
  __syncthreads();
  for (int off = 1; off < 1024; off <<= 1) {
    int add = (t >= off) ? s1[t - off] : 0;
    __syncthreads();
    s1[t] += add;
    __syncthreads();
  }
  int run = s1[t] - sum;  // exclusive prefix of this chunk
  for (int i = 0; i < PER; ++i) {
    int hv = hist[base + i];
    start[base + i] = run;
    cursor[base + i] = run;
    run += hv;
  }
  if (t == 1023) start[2 * B_N] = run;
}

__global__ __launch_bounds__(256) void k_scatter(
    const int* __restrict__ prow, const int* __restrict__ pcol,
    const int* __restrict__ nrow, const int* __restrict__ ncol,
    int* __restrict__ cursor, int* __restrict__ cols_s)
{
  int i = blockIdx.x * 256 + threadIdx.x;
  int r, c;
  if (i < E_N) { r = prow[i]; c = pcol[i]; }
  else if (i < 2 * E_N) { r = B_N + nrow[i - E_N]; c = ncol[i - E_N]; }
  else return;
  int pos = atomicAdd(&cursor[r], 1);
  cols_s[pos] = c;
}

// Aggregation: one 32-lane group per (branch,row). No atomics; fused elu+out.
__global__ __launch_bounds__(256) void k_agg(
    const int* __restrict__ start, const int* __restrict__ cols_s,
    const int* __restrict__ selfc,
    const unsigned short* __restrict__ hb, const unsigned short* __restrict__ hu,
    const float* __restrict__ adb, const float* __restrict__ asb,
    const float* __restrict__ adu, const float* __restrict__ asu,
    float* __restrict__ out)
{
  int g = blockIdx.x * 8 + (threadIdx.x >> 5);
  int lane = threadIdx.x & 31;
  if (g >= 2 * B_N) return;
  int br = g >> 16;
  int r = g & (B_N - 1);
  const unsigned short* h = br ? hu : hb;
  const float* adst = br ? adu : adb;
  float asr = (br ? asu : asb)[r];

  int c0 = selfc[r];
  float acc, den;
  {
    float s = asr + adst[c0];
    float sc = s > 0.f ? s : 0.2f * s;
    float ev = __expf(-sc);
    acc = ev * bf2f(h[((size_t)c0 << 5) + lane]);
    den = ev;
  }

  int s0 = start[g], s1 = start[g + 1];
  for (int base = s0; base < s1; base += 32) {
    int nrem = s1 - base;
    int m = nrem < 32 ? nrem : 32;
    int c = (lane < nrem) ? cols_s[base + lane] : c0;
    float ad = adst[c];  // per-lane gather, mostly L2/L3 hits
    float s = asr + ad;
    float sc = s > 0.f ? s : 0.2f * s;
    float ev = (lane < nrem) ? __expf(-sc) : 0.f;
    // den: reduce ev across the 32-lane group
    float evs = ev;
    #pragma unroll
    for (int off = 16; off > 0; off >>= 1) evs += __shfl_xor(evs, off, 32);
    den += evs;
    // acc: serial over edges in this chunk, loads independent -> pipeline
    for (int j = 0; j < m; ++j) {
      int cj = __shfl(c, j, 32);
      float evj = __shfl(ev, j, 32);
      acc = fmaf(evj, bf2f(h[((size_t)cj << 5) + lane]), acc);
    }
  }

  float x = acc / den;
  out[((size_t)g << 5) + lane] = (x > 0.f) ? x : (__expf(x) - 1.f);
}

extern "C" void kernel_launch(void* const* d_in, const int* in_sizes, int n_in,
                              void* d_out, int out_size, void* d_ws, size_t ws_size,
                              hipStream_t stream) {
  const float* emb = (const float*)d_in[0];
  const float* Wb  = (const float*)d_in[1];
  const float* ab  = (const float*)d_in[2];
  const float* Wu  = (const float*)d_in[3];
  const float* au  = (const float*)d_in[4];
  const int* uids  = (const int*)d_in[5];
  const int* selfc = (const int*)d_in[6];
  const int* prow  = (const int*)d_in[7];
  const int* pcol  = (const int*)d_in[8];
  const int* nrow  = (const int*)d_in[9];
  const int* ncol  = (const int*)d_in[10];
  float* out = (float*)d_out;

  char* ws = (char*)d_ws;
  size_t off = 0;
  auto alloc = [&](size_t bytes) -> void* {
    void* p = ws + off;
    off += (bytes + 255) & ~(size_t)255;
    return p;
  };
  unsigned short* hb = (unsigned short*)alloc((size_t)M_N * OUT_D * 2);
  unsigned short* hu = (unsigned short*)alloc((size_t)M_N * OUT_D * 2);
  float* adb = (float*)alloc((size_t)M_N * 4);
  float* adu = (float*)alloc((size_t)M_N * 4);
  float* asb = (float*)alloc((size_t)B_N * 4);
  float* asu = (float*)alloc((size_t)B_N * 4);
  int* hist   = (int*)alloc((size_t)2 * B_N * 4);
  int* start  = (int*)alloc(((size_t)2 * B_N + 1) * 4);
  int* cursor = (int*)alloc((size_t)2 * B_N * 4);
  int* cols_s = (int*)alloc((size_t)2 * E_N * 4);

  hipMemsetAsync(hist, 0, (size_t)2 * B_N * 4, stream);

  k_hist<<<(2 * E_N + 255) / 256, 256, 0, stream>>>(prow, nrow, hist);
  k_scan<<<1, 1024, 0, stream>>>(hist, start, cursor);
  k_scatter<<<(2 * E_N + 255) / 256, 256, 0, stream>>>(prow, pcol, nrow, ncol,
                                                       cursor, cols_s);

  k_hproj<<<(M_N + 255) / 256, 256, 0, stream>>>(emb, Wb, ab, Wu, au, uids,
                                                 hb, hu, adb, adu, asb, asu);

  k_agg<<<(2 * B_N + 7) / 8, 256, 0, stream>>>(start, cols_s, selfc,
                                               hb, hu, adb, asb, adu, asu, out);
}

// Round 5
// 568.315 us; speedup vs baseline: 1.7177x; 1.3694x over previous
//
#include <hip/hip_runtime.h>

#define B_N 65536
#define M_N 1000000
#define E_N 1310720
#define IN_D 64
#define OUT_D 32
#define XS2 72   // sx row stride in SHORTS (144 B, 16B-aligned rows)
#define NCT 5    // col-tiles: 4 x 16 h-cols + 1 tile holding folded a-dot cols
#define NFRAG (NCT * 2)

typedef __attribute__((ext_vector_type(8))) short bf16x8;
typedef __attribute__((ext_vector_type(4))) float f32x4;

__device__ __forceinline__ unsigned short f2bf(float f) {
  unsigned u = __float_as_uint(f);
  u += 0x7fffu + ((u >> 16) & 1u);
  return (unsigned short)(u >> 16);
}
__device__ __forceinline__ unsigned pk2(float a, float b) {
  return (unsigned)f2bf(a) | ((unsigned)f2bf(b) << 16);
}
__device__ __forceinline__ float bf2f(unsigned short s) {
  return __uint_as_float(((unsigned)s) << 16);
}

// Pre-pack B_ext = [Wb | Wu | Wb@ab_lo | Wb@ab_hi | Wu@au_lo | Wu@au_hi | 0..]
// (64 k x 80 n, bf16) directly in MFMA B-fragment lane order:
// frag q = ct*2+S; lane l elem i: k = 32*S + 8*(l>>4) + i, n = 16*ct + (l&15).
__global__ __launch_bounds__(256) void k_fold(
    const float* __restrict__ Wb, const float* __restrict__ ab,
    const float* __restrict__ Wu, const float* __restrict__ au,
    unsigned* __restrict__ frag_buf)  // [NFRAG][64][4] dwords
{
  int t = threadIdx.x;
  for (int p = t; p < NFRAG * 64 * 4; p += 256) {
    int q = p >> 8;
    int rem = p & 255;
    int l = rem >> 2;
    int d = rem & 3;
    int ct = q >> 1, S = q & 1;
    int kb = 32 * S + 8 * (l >> 4);
    int n = 16 * ct + (l & 15);
    float v[2];
    #pragma unroll
    for (int e = 0; e < 2; ++e) {
      int kk = kb + 2 * d + e;
      float val;
      if (n < 32) val = Wb[kk * 32 + n];
      else if (n < 64) val = Wu[kk * 32 + (n - 32)];
      else if (n < 68) {
        const float* W = (n < 66) ? Wb : Wu;
        const float* av = (n < 66) ? ab : au;
        int hi = (n & 1) ? 32 : 0;
        float acc = 0.f;
        for (int j = 0; j < 32; ++j) acc = fmaf(W[kk * 32 + j], av[hi + j], acc);
        val = acc;
      } else val = 0.f;
      v[e] = val;
    }
    frag_buf[p] = pk2(v[0], v[1]);
  }
}

// MFMA h-projection: block = 256 rows; wave computes 64 rows x 80 cols.
// Outputs: hb/hu (bf16), adb/adu (all rows), asb/asu (rows < B_N).
__global__ __launch_bounds__(256) void k_hproj(
    const float* __restrict__ emb, const int* __restrict__ uids,
    const unsigned* __restrict__ frag_buf,
    unsigned short* __restrict__ hb, unsigned short* __restrict__ hu,
    float* __restrict__ adb, float* __restrict__ adu,
    float* __restrict__ asb, float* __restrict__ asu)
{
  __shared__ int suid[256];
  __shared__ unsigned short sx[256 * XS2];
  int t = threadIdx.x;
  int nbase = blockIdx.x * 256;
  suid[t] = (nbase + t < M_N) ? uids[nbase + t] : 0;
  __syncthreads();

  // Stage 256 emb rows as bf16: thread t handles 16B-chunk (t&15) of rows
  // 16i + (t>>4). Coalesced 1KB/wave-instr global reads, conflict-free writes.
  int chunk = t & 15, rb = t >> 4;
  #pragma unroll 4
  for (int i = 0; i < 16; ++i) {
    int row = i * 16 + rb;
    float4 v = ((const float4*)emb)[(size_t)suid[row] * 16 + chunk];
    uint2 p;
    p.x = pk2(v.x, v.y);
    p.y = pk2(v.z, v.w);
    *(uint2*)&sx[row * XS2 + chunk * 4] = p;
  }
  __syncthreads();

  int l = t & 63, w = t >> 6;
  // B fragments: 10 coalesced 16B loads (L2-hot 10KB table).
  bf16x8 bf[NFRAG];
  #pragma unroll
  for (int q = 0; q < NFRAG; ++q)
    bf[q] = *(const bf16x8*)&frag_buf[(q * 64 + l) * 4];

  f32x4 acc[4][NCT];
  #pragma unroll
  for (int rt = 0; rt < 4; ++rt)
    #pragma unroll
    for (int ct = 0; ct < NCT; ++ct)
      acc[rt][ct] = (f32x4){0.f, 0.f, 0.f, 0.f};

  int wr0 = w * 64;
  #pragma unroll
  for (int rt = 0; rt < 4; ++rt) {
    const unsigned short* arow =
        &sx[(wr0 + rt * 16 + (l & 15)) * XS2 + (l >> 4) * 8];
    bf16x8 a0 = *(const bf16x8*)(arow);        // k 0..31 slice
    bf16x8 a1 = *(const bf16x8*)(arow + 32);   // k 32..63 slice
    #pragma unroll
    for (int ct = 0; ct < NCT; ++ct) {
      acc[rt][ct] = __builtin_amdgcn_mfma_f32_16x16x32_bf16(
          a0, bf[2 * ct + 0], acc[rt][ct], 0, 0, 0);
      acc[rt][ct] = __builtin_amdgcn_mfma_f32_16x16x32_bf16(
          a1, bf[2 * ct + 1], acc[rt][ct], 0, 0, 0);
    }
  }

  // Epilogue. D: col = lane&15, row = (lane>>4)*4 + reg (m89-verified).
  int g = l >> 4, cc = l & 15;
  #pragma unroll
  for (int rt = 0; rt < 4; ++rt) {
    #pragma unroll
    for (int r = 0; r < 4; ++r) {
      int row = nbase + wr0 + rt * 16 + g * 4 + r;
      if (row < M_N) {
        #pragma unroll
        for (int ct = 0; ct < 4; ++ct) {
          unsigned short hv = f2bf(acc[rt][ct][r]);
          if (ct < 2) hb[(size_t)row * 32 + ct * 16 + cc] = hv;
          else hu[(size_t)row * 32 + (ct - 2) * 16 + cc] = hv;
        }
        float dv = acc[rt][4][r];
        if (cc == 1) adb[row] = dv;
        else if (cc == 3) adu[row] = dv;
        else if (cc == 0) { if (row < B_N) asb[row] = dv; }
        else if (cc == 2) { if (row < B_N) asu[row] = dv; }
      }
    }
  }
}

// Counting sort of edges by (branch, row) -> CSR.
__global__ __launch_bounds__(256) void k_hist(
    const int* __restrict__ prow, const int* __restrict__ nrow,
    int* __restrict__ hist)
{
  int i = blockIdx.x * 256 + threadIdx.x;
  if (i < E_N) atomicAdd(&hist[prow[i]], 1);
  else if (i < 2 * E_N) atomicAdd(&hist[B_N + nrow[i - E_N]], 1);
}

__global__ __launch_bounds__(1024) void k_scan(
    const int* __restrict__ hist,
    int* __restrict__ start, int* __restrict__ cursor)
{
  __shared__ int s1[1024];
  int t = threadIdx.x;
  const int PER = (2 * B_N) / 1024;  // 128
  int base = t * PER;
  int sum = 0;
  for (int i = 0; i < PER; ++i) sum += hist[base + i];
  s1[t] = sum;
  __syncthreads();
  for (int off = 1; off < 1024; off <<= 1) {
    int add = (t >= off) ? s1[t - off] : 0;
    __syncthreads();
    s1[t] += add;
    __syncthreads();
  }
  int run = s1[t] - sum;
  for (int i = 0; i < PER; ++i) {
    int hv = hist[base + i];
    start[base + i] = run;
    cursor[base + i] = run;
    run += hv;
  }
  if (t == 1023) start[2 * B_N] = run;
}

__global__ __launch_bounds__(256) void k_scatter(
    const int* __restrict__ prow, const int* __restrict__ pcol,
    const int* __restrict__ nrow, const int* __restrict__ ncol,
    int* __restrict__ cursor, int* __restrict__ cols_s)
{
  int i = blockIdx.x * 256 + threadIdx.x;
  int r, c;
  if (i < E_N) { r = prow[i]; c = pcol[i]; }
  else if (i < 2 * E_N) { r = B_N + nrow[i - E_N]; c = ncol[i - E_N]; }
  else return;
  int pos = atomicAdd(&cursor[r], 1);
  cols_s[pos] = c;
}

// Aggregation: one 32-lane group per (branch,row); no atomics; fused elu+out.
// Inner loop unrolled x8 so the h-row gathers issue independently.
__global__ __launch_bounds__(256) void k_agg(
    const int* __restrict__ start, const int* __restrict__ cols_s,
    const int* __restrict__ selfc,
    const unsigned short* __restrict__ hb, const unsigned short* __restrict__ hu,
    const float* __restrict__ adb, const float* __restrict__ asb,
    const float* __restrict__ adu, const float* __restrict__ asu,
    float* __restrict__ out)
{
  int g = blockIdx.x * 8 + (threadIdx.x >> 5);
  int lane = threadIdx.x & 31;
  if (g >= 2 * B_N) return;
  int br = g >> 16;
  int r = g & (B_N - 1);
  const unsigned short* h = br ? hu : hb;
  const float* adst = br ? adu : adb;
  float asr = (br ? asu : asb)[r];

  int c0 = selfc[r];
  float acc, den;
  {
    float s = asr + adst[c0];
    float sc = s > 0.f ? s : 0.2f * s;
    float ev = __expf(-sc);
    acc = ev * bf2f(h[((size_t)c0 << 5) + lane]);
    den = ev;
  }

  int s0 = start[g], s1 = start[g + 1];
  for (int base = s0; base < s1; base += 32) {
    int rem = s1 - base;
    int c = (lane < rem) ? cols_s[base + lane] : c0;
    float ad = adst[c];
    float s = asr + ad;
    float sc = s > 0.f ? s : 0.2f * s;
    float ev = (lane < rem) ? __expf(-sc) : 0.f;
    float evs = ev;
    #pragma unroll
    for (int off = 16; off > 0; off >>= 1) evs += __shfl_xor(evs, off, 32);
    den += evs;

    int m = rem < 32 ? rem : 32;
    int mr = (m + 7) & ~7;  // j+q stays < 32: no shfl wraparound
    for (int j = 0; j < mr; j += 8) {
      int cj[8];
      float ej[8];
      #pragma unroll
      for (int q = 0; q < 8; ++q) {
        cj[q] = __shfl(c, j + q, 32);
        ej[q] = __shfl(ev, j + q, 32);
      }
      float hv[8];
      #pragma unroll
      for (int q = 0; q < 8; ++q)
        hv[q] = bf2f(h[((size_t)cj[q] << 5) + lane]);
      #pragma unroll
      for (int q = 0; q < 8; ++q) acc = fmaf(ej[q], hv[q], acc);
    }
  }

  float x = acc / den;
  out[((size_t)g << 5) + lane] = (x > 0.f) ? x : (__expf(x) - 1.f);
}

extern "C" void kernel_launch(void* const* d_in, const int* in_sizes, int n_in,
                              void* d_out, int out_size, void* d_ws, size_t ws_size,
                              hipStream_t stream) {
  const float* emb = (const float*)d_in[0];
  const float* Wb  = (const float*)d_in[1];
  const float* ab  = (const float*)d_in[2];
  const float* Wu  = (const float*)d_in[3];
  const float* au  = (const float*)d_in[4];
  const int* uids  = (const int*)d_in[5];
  const int* selfc = (const int*)d_in[6];
  const int* prow  = (const int*)d_in[7];
  const int* pcol  = (const int*)d_in[8];
  const int* nrow  = (const int*)d_in[9];
  const int* ncol  = (const int*)d_in[10];
  float* out = (float*)d_out;

  char* ws = (char*)d_ws;
  size_t off = 0;
  auto alloc = [&](size_t bytes) -> void* {
    void* p = ws + off;
    off += (bytes + 255) & ~(size_t)255;
    return p;
  };
  unsigned short* hb = (unsigned short*)alloc((size_t)M_N * OUT_D * 2);
  unsigned short* hu = (unsigned short*)alloc((size_t)M_N * OUT_D * 2);
  float* adb = (float*)alloc((size_t)M_N * 4);
  float* adu = (float*)alloc((size_t)M_N * 4);
  float* asb = (float*)alloc((size_t)B_N * 4);
  float* asu = (float*)alloc((size_t)B_N * 4);
  int* hist   = (int*)alloc((size_t)2 * B_N * 4);
  int* start  = (int*)alloc(((size_t)2 * B_N + 1) * 4);
  int* cursor = (int*)alloc((size_t)2 * B_N * 4);
  int* cols_s = (int*)alloc((size_t)2 * E_N * 4);
  unsigned* frag_buf = (unsigned*)alloc((size_t)NFRAG * 64 * 4 * 4);

  hipMemsetAsync(hist, 0, (size_t)2 * B_N * 4, stream);

  k_fold<<<1, 256, 0, stream>>>(Wb, ab, Wu, au, frag_buf);
  k_hist<<<(2 * E_N + 255) / 256, 256, 0, stream>>>(prow, nrow, hist);
  k_scan<<<1, 1024, 0, stream>>>(hist, start, cursor);
  k_scatter<<<(2 * E_N + 255) / 256, 256, 0, stream>>>(prow, pcol, nrow, ncol,
                                                       cursor, cols_s);

  k_hproj<<<(M_N + 255) / 256, 256, 0, stream>>>(emb, uids, frag_buf,
                                                 hb, hu, adb, adu, asb, asu);

  k_agg<<<(2 * B_N + 7) / 8, 256, 0, stream>>>(start, cols_s, selfc,
                                               hb, hu, adb, asb, adu, asu, out);
}